// Round 9
// baseline (291.631 us; speedup 1.0000x reference)
//
#include <hip/hip_runtime.h>
#include <hip/hip_bf16.h>
#include <cstdint>
#include <cstddef>

#define B_  16
#define S_  512
#define E_  768
#define NH_ 12
#define D_  64
#define M_  (B_*S_)   // 8192

typedef unsigned short u16;
typedef __attribute__((ext_vector_type(4))) float f32x4;
typedef __attribute__((ext_vector_type(8))) short bf16x8;

#define LOG2E 1.4426950408889634f

__device__ __forceinline__ u16 f2bf(float f){
  union { float fv; uint32_t u; } v; v.fv = f;
  uint32_t u = v.u;
  uint32_t r = u + 0x7fffu + ((u >> 16) & 1u);   // RNE
  return (u16)(r >> 16);
}

// ---------------- prep: cast X (blocks 0..6143) + transpose W (blocks 6144..7871) ----------------
__global__ __launch_bounds__(256) void prep_kernel(
    const float* __restrict__ X, u16* __restrict__ Xb,
    const float* __restrict__ Wq, const float* __restrict__ Wk,
    const float* __restrict__ Wv, u16* __restrict__ WtBase)
{
  __shared__ float t[32][33];
  const int bx = blockIdx.x;
  if (bx < 6144){
    int i = bx * 256 + threadIdx.x;          // n4 = 8192*768/4 = 1572864 exactly
    float4 v = reinterpret_cast<const float4*>(X)[i];
    ushort4 o;
    o.x = f2bf(v.x); o.y = f2bf(v.y); o.z = f2bf(v.z); o.w = f2bf(v.w);
    reinterpret_cast<ushort4*>(Xb)[i] = o;
  } else {
    int tt = bx - 6144;                      // 0..1727 = 24*24*3
    int z = tt / 576, rem = tt % 576;
    int byi = rem / 24, bxi = rem % 24;
    const float* W = (z == 0) ? Wq : ((z == 1) ? Wk : Wv);
    u16* Wt = WtBase + (size_t)z * E_ * E_;
    int bx0 = bxi * 32, by0 = byi * 32;
    int tx = threadIdx.x & 31, ty = threadIdx.x >> 5;
    #pragma unroll
    for (int i = 0; i < 32; i += 8)
      t[ty + i][tx] = W[(size_t)(by0 + ty + i) * E_ + bx0 + tx];
    __syncthreads();
    #pragma unroll
    for (int i = 0; i < 32; i += 8)
      Wt[(size_t)(bx0 + ty + i) * E_ + by0 + tx] = f2bf(t[tx][ty + i]);
  }
}

// ---------------- fused QKV GEMM: C = Xb(8192x768) @ W(768x768) + bias ----------------
// BK=32, LDS double-buffer + register prefetch, ONE barrier/iter.
// __launch_bounds__(256, 2): min 2 waves/EU -> VGPR budget 256/wave, so the
// ~140-reg working set (64 acc + 32 frag + 16 staged + addr) allocates WITHOUT
// the scratch spill that killed R3/R8 (WRITE_SIZE 37->79MB at the default
// occupancy target's 88-reg cap). ILP replaces TLP: prefetch issued right
// after the barrier has the whole MFMA+LDS phase of all waves to land.
// Coalesced staging (4 lanes cover a row's 64B) + XOR slot swizzle: 0 conflicts.
__global__ __launch_bounds__(256, 2) void qkv_gemm_kernel(
    const u16* __restrict__ Xb, const u16* __restrict__ WtBase,
    const float* __restrict__ bq, const float* __restrict__ bk, const float* __restrict__ bv,
    u16* __restrict__ Qb, u16* __restrict__ Kb, u16* __restrict__ VtB)
{
  __shared__ u16 lA[2][8 * 512];   // 8 chunks x 1KB per buffer (chunk = 16 rows x 32 k)
  __shared__ u16 lB[2][8 * 512];
  const int z = blockIdx.z;
  const u16* Wt = WtBase + (size_t)z * E_ * E_;
  const float* bias = (z == 0) ? bq : ((z == 1) ? bk : bv);
  const int m0 = blockIdx.x * 128;
  const int n0 = blockIdx.y * 128;
  const int tid = threadIdx.x;
  const int lane = tid & 63;
  const int wave = tid >> 6;
  const int wm = wave & 1, wn = wave >> 1;       // 2x2 waves of 64x64
  const int col0 = lane & 15, quad = lane >> 4;
  const int srow = lane >> 2, soct = lane & 3;   // coalesced: 4 lanes = one row's 64B
  const int sslot = soct*16 + (srow ^ (soct << 1));
  const int rslot = quad*16 + (col0 ^ (quad << 1));

  f32x4 acc[4][4];
  #pragma unroll
  for (int i = 0; i < 4; ++i)
    #pragma unroll
    for (int j = 0; j < 4; ++j)
      acc[i][j] = (f32x4){0.f, 0.f, 0.f, 0.f};

  uint4 va[2], vb[2];
  auto issue = [&](int k0){
    #pragma unroll
    for (int cc = 0; cc < 2; ++cc){
      int c = wave * 2 + cc;
      va[cc] = *reinterpret_cast<const uint4*>(Xb + (size_t)(m0 + c*16 + srow) * E_ + k0 + soct*8);
      vb[cc] = *reinterpret_cast<const uint4*>(Wt + (size_t)(n0 + c*16 + srow) * E_ + k0 + soct*8);
    }
  };
  issue(0);

  #pragma unroll 1
  for (int it = 0; it < 24; ++it){
    const int cur = it & 1;
    #pragma unroll
    for (int cc = 0; cc < 2; ++cc){
      int c = wave * 2 + cc;
      *reinterpret_cast<uint4*>(&lA[cur][c*512 + sslot*8]) = va[cc];
      *reinterpret_cast<uint4*>(&lB[cur][c*512 + sslot*8]) = vb[cc];
    }
    __syncthreads();            // single barrier: buf[cur]'s last readers finished before iter it-1's barrier
    if (it + 1 < 24) issue((it + 1) * 32);   // prefetch during compute
    bf16x8 af[4], bfr[4];
    #pragma unroll
    for (int mi = 0; mi < 4; ++mi)
      af[mi] = *reinterpret_cast<const bf16x8*>(&lA[cur][(wm*4 + mi)*512 + rslot*8]);
    #pragma unroll
    for (int ni = 0; ni < 4; ++ni)
      bfr[ni] = *reinterpret_cast<const bf16x8*>(&lB[cur][(wn*4 + ni)*512 + rslot*8]);
    #pragma unroll
    for (int mi = 0; mi < 4; ++mi)
      #pragma unroll
      for (int ni = 0; ni < 4; ++ni)
        acc[mi][ni] = __builtin_amdgcn_mfma_f32_16x16x32_bf16(af[mi], bfr[ni], acc[mi][ni], 0, 0, 0);
  }

  // epilogue: C col = n = lane&15, row = m = quad*4+r
  #pragma unroll
  for (int mi = 0; mi < 4; ++mi){
    #pragma unroll
    for (int ni = 0; ni < 4; ++ni){
      int n = n0 + wn*64 + ni*16 + col0;
      float bval = bias[n];
      int h = n >> 6, d = n & 63;
      #pragma unroll
      for (int r = 0; r < 4; ++r){
        int m = m0 + wm*64 + mi*16 + quad*4 + r;
        int b = m >> 9, s = m & 511;
        u16 obf = f2bf(acc[mi][ni][r] + bval);
        size_t bh = (size_t)b * NH_ + h;
        if (z == 0)      Qb[(bh * S_ + s) * D_ + d] = obf;
        else if (z == 1) Kb[(bh * S_ + s) * D_ + d] = obf;
        else             VtB[(bh * D_ + d) * S_ + s] = obf;  // transposed for attention
      }
    }
  }
}

// ---------------- flash attention (unchanged from R8) ----------------
__global__ __launch_bounds__(256) void attn_kernel(
    const u16* __restrict__ Qb, const u16* __restrict__ Kb, const u16* __restrict__ VtB,
    const float* __restrict__ mask, float* __restrict__ out)
{
  __shared__ u16 lK[2][8 * 512];   // 16 KB
  __shared__ u16 lV[2][8 * 512];   // 16 KB
  __shared__ u16 lP[8 * 1024];     // 16 KB: (wave*2+g)*1024, per-wave (no barrier)
  __shared__ float biasS[S_];
  const int bh = blockIdx.x;
  const int qt = blockIdx.y;
  const int b = bh / NH_, h = bh % NH_;
  const int tid = threadIdx.x, lane = tid & 63, wave = tid >> 6;
  const int col0 = lane & 15, quad = lane >> 4;
  const int srow = lane >> 2, soct = lane & 3;   // coalesced staging
  const int sslot = soct*16 + (srow ^ (soct << 1));
  const int rslot = quad*16 + (col0 ^ (quad << 1));
  const float C1 = 0.125f * LOG2E;               // score scale folded with log2e

  for (int i = tid; i < S_; i += 256)
    biasS[i] = mask[b * S_ + i] * (-1.0e9f * LOG2E);   // exp2 domain; visible after iter-0 barrier

  const u16* Kbh = Kb  + (size_t)bh * S_ * D_;
  const u16* Vbh = VtB + (size_t)bh * D_ * S_;

  // Q fragments: 2 groups x 16 rows (B-operand; same layout as A)
  bf16x8 qf[2][2];
  #pragma unroll
  for (int g = 0; g < 2; ++g){
    int qrow = qt*128 + wave*32 + g*16 + col0;
    #pragma unroll
    for (int ks = 0; ks < 2; ++ks)
      qf[g][ks] = *reinterpret_cast<const bf16x8*>(
          Qb + ((size_t)bh * S_ + qrow) * D_ + ks*32 + quad*8);
  }

  // staging: waves 0-1 -> 8 K chunks, waves 2-3 -> 8 Vt chunks
  uint4 rg[4];
  auto issue = [&](int st){
    if (wave < 2){
      #pragma unroll
      for (int gg = 0; gg < 4; ++gg){
        int c = wave*4 + gg, ks = c >> 2, nt = c & 3;
        rg[gg] = *reinterpret_cast<const uint4*>(
            Kbh + (size_t)(st*64 + nt*16 + srow) * D_ + ks*32 + soct*8);
      }
    } else {
      #pragma unroll
      for (int gg = 0; gg < 4; ++gg){
        int c = (wave - 2)*4 + gg, ks2 = c >> 2, nd = c & 3;
        rg[gg] = *reinterpret_cast<const uint4*>(
            Vbh + (size_t)(nd*16 + srow) * S_ + st*64 + ks2*32 + soct*8);
      }
    }
  };
  issue(0);

  f32x4 o[2][4];
  #pragma unroll
  for (int g = 0; g < 2; ++g)
    #pragma unroll
    for (int i = 0; i < 4; ++i) o[g][i] = (f32x4){0.f, 0.f, 0.f, 0.f};
  float psum[2] = {0.f, 0.f};   // per-lane partial row-sums

  #pragma unroll 1
  for (int st = 0; st < 8; ++st){
    const int cur = st & 1;
    if (wave < 2){
      #pragma unroll
      for (int gg = 0; gg < 4; ++gg)
        *reinterpret_cast<uint4*>(&lK[cur][(wave*4 + gg)*512 + sslot*8]) = rg[gg];
    } else {
      #pragma unroll
      for (int gg = 0; gg < 4; ++gg)
        *reinterpret_cast<uint4*>(&lV[cur][((wave - 2)*4 + gg)*512 + sslot*8]) = rg[gg];
    }
    __syncthreads();            // single barrier/iter
    if (st < 7) issue(st + 1);  // prefetch during compute

    // scores transposed, both groups: 64 keys (rows) x 16 q (cols)
    f32x4 sc[2][4];
    #pragma unroll
    for (int g = 0; g < 2; ++g)
      #pragma unroll
      for (int nt = 0; nt < 4; ++nt) sc[g][nt] = (f32x4){0.f, 0.f, 0.f, 0.f};
    #pragma unroll
    for (int ks = 0; ks < 2; ++ks){
      bf16x8 kf[4];
      #pragma unroll
      for (int nt = 0; nt < 4; ++nt)
        kf[nt] = *reinterpret_cast<const bf16x8*>(&lK[cur][(ks*4 + nt)*512 + rslot*8]);
      #pragma unroll
      for (int g = 0; g < 2; ++g)
        #pragma unroll
        for (int nt = 0; nt < 4; ++nt)
          sc[g][nt] = __builtin_amdgcn_mfma_f32_16x16x32_bf16(kf[nt], qf[g][ks], sc[g][nt], 0, 0, 0);
    }

    float4 bb[4];
    #pragma unroll
    for (int nt = 0; nt < 4; ++nt)
      bb[nt] = *reinterpret_cast<const float4*>(&biasS[st*64 + nt*16 + quad*4]);

    #pragma unroll
    for (int g = 0; g < 2; ++g){
      #pragma unroll
      for (int nt = 0; nt < 4; ++nt){
        float p0 = exp2f(sc[g][nt][0] * C1 + bb[nt].x);
        float p1 = exp2f(sc[g][nt][1] * C1 + bb[nt].y);
        float p2 = exp2f(sc[g][nt][2] * C1 + bb[nt].z);
        float p3 = exp2f(sc[g][nt][3] * C1 + bb[nt].w);
        psum[g] += (p0 + p1) + (p2 + p3);
        float2 ab; ab.x = p0; ab.y = p1;
        float2 cd; cd.x = p2; cd.y = p3;
        __hip_bfloat162 h01 = __float22bfloat162_rn(ab);
        __hip_bfloat162 h23 = __float22bfloat162_rn(cd);
        uint2 pw;
        pw.x = *reinterpret_cast<unsigned int*>(&h01);
        pw.y = *reinterpret_cast<unsigned int*>(&h23);
        // A-layout addr: chunk=nt>>1, slot=((nt&1)*2+(quad>>1))*16+q, u16 pos=(quad&1)*4+r
        int addr = (wave*2 + g)*1024 + (nt >> 1)*512
                 + (((nt & 1)*2 + (quad >> 1))*16 + col0)*8 + (quad & 1)*4;
        *reinterpret_cast<uint2*>(&lP[addr]) = pw;
      }
    }

    // PV: shared V fragments serve both groups
    #pragma unroll
    for (int ks2 = 0; ks2 < 2; ++ks2){
      bf16x8 pf0 = *reinterpret_cast<const bf16x8*>(&lP[(wave*2 + 0)*1024 + ks2*512 + lane*8]);
      bf16x8 pf1 = *reinterpret_cast<const bf16x8*>(&lP[(wave*2 + 1)*1024 + ks2*512 + lane*8]);
      #pragma unroll
      for (int nd = 0; nd < 4; ++nd){
        bf16x8 vf = *reinterpret_cast<const bf16x8*>(&lV[cur][(ks2*4 + nd)*512 + rslot*8]);
        o[0][nd] = __builtin_amdgcn_mfma_f32_16x16x32_bf16(pf0, vf, o[0][nd], 0, 0, 0);
        o[1][nd] = __builtin_amdgcn_mfma_f32_16x16x32_bf16(pf1, vf, o[1][nd], 0, 0, 0);
      }
    }
  }

  // epilogue: finish row-sums (once), normalize, store fp32
  #pragma unroll
  for (int g = 0; g < 2; ++g){
    float tot = psum[g];
    tot += __shfl_xor(tot, 16, 64);
    tot += __shfl_xor(tot, 32, 64);
    #pragma unroll
    for (int r = 0; r < 4; ++r){
      int s = qt*128 + wave*32 + g*16 + quad*4 + r;
      float lr = __shfl(tot, (lane & 48) | (quad*4 + r), 64);
      float inv = 1.0f / lr;
      #pragma unroll
      for (int nd = 0; nd < 4; ++nd){
        int d = nd*16 + col0;
        out[((size_t)b * S_ + s) * E_ + h*D_ + d] = o[g][nd][r] * inv;
      }
    }
  }
}

extern "C" void kernel_launch(void* const* d_in, const int* in_sizes, int n_in,
                              void* d_out, int out_size, void* d_ws, size_t ws_size,
                              hipStream_t stream){
  const float* X    = (const float*)d_in[0];
  const float* mask = (const float*)d_in[1];
  const float* Wq   = (const float*)d_in[2];
  const float* bq   = (const float*)d_in[3];
  const float* Wk   = (const float*)d_in[4];
  const float* bk   = (const float*)d_in[5];
  const float* Wv   = (const float*)d_in[6];
  const float* bv   = (const float*)d_in[7];
  float* out = (float*)d_out;

  // workspace layout (bf16): Xb | Wt x3 | Qb | Kb | Vt  (~51.4 MB total)
  u16* Xb = (u16*)d_ws;
  u16* Wt = Xb + (size_t)M_ * E_;
  u16* Qb = Wt + (size_t)3 * E_ * E_;
  u16* Kb = Qb + (size_t)M_ * E_;
  u16* Vt = Kb + (size_t)M_ * E_;

  prep_kernel<<<6144 + 1728, 256, 0, stream>>>(X, Xb, Wq, Wk, Wv, Wt);
  qkv_gemm_kernel<<<dim3(64, 6, 3), 256, 0, stream>>>(Xb, Wt, bq, bk, bv, Qb, Kb, Vt);
  attn_kernel<<<dim3(192, 4), 256, 0, stream>>>(Qb, Kb, Vt, mask, out);
}

// Round 10
// 216.313 us; speedup vs baseline: 1.3482x; 1.3482x over previous
//
#include <hip/hip_runtime.h>
#include <hip/hip_bf16.h>
#include <cstdint>
#include <cstddef>

#define B_  16
#define S_  512
#define E_  768
#define NH_ 12
#define D_  64
#define M_  (B_*S_)   // 8192

typedef unsigned short u16;
typedef __attribute__((ext_vector_type(4))) float f32x4;
typedef __attribute__((ext_vector_type(8))) short bf16x8;

#define LOG2E 1.4426950408889634f

__device__ __forceinline__ u16 f2bf(float f){
  union { float fv; uint32_t u; } v; v.fv = f;
  uint32_t u = v.u;
  uint32_t r = u + 0x7fffu + ((u >> 16) & 1u);   // RNE
  return (u16)(r >> 16);
}

// async global->LDS DMA, 16B per lane; HW deposits lane L at ldsbase + L*16.
__device__ __forceinline__ void gload_lds16(const void* g, void* ldsbase){
  __builtin_amdgcn_global_load_lds(
      (const __attribute__((address_space(1))) unsigned int*)g,
      (__attribute__((address_space(3))) unsigned int*)ldsbase, 16, 0, 0);
}

// ---------------- prep: cast X (blocks 0..6143) + transpose W (blocks 6144..7871) ----------------
__global__ __launch_bounds__(256) void prep_kernel(
    const float* __restrict__ X, u16* __restrict__ Xb,
    const float* __restrict__ Wq, const float* __restrict__ Wk,
    const float* __restrict__ Wv, u16* __restrict__ WtBase)
{
  __shared__ float t[32][33];
  const int bx = blockIdx.x;
  if (bx < 6144){
    int i = bx * 256 + threadIdx.x;          // n4 = 8192*768/4 = 1572864 exactly
    float4 v = reinterpret_cast<const float4*>(X)[i];
    ushort4 o;
    o.x = f2bf(v.x); o.y = f2bf(v.y); o.z = f2bf(v.z); o.w = f2bf(v.w);
    reinterpret_cast<ushort4*>(Xb)[i] = o;
  } else {
    int tt = bx - 6144;                      // 0..1727 = 24*24*3
    int z = tt / 576, rem = tt % 576;
    int byi = rem / 24, bxi = rem % 24;
    const float* W = (z == 0) ? Wq : ((z == 1) ? Wk : Wv);
    u16* Wt = WtBase + (size_t)z * E_ * E_;
    int bx0 = bxi * 32, by0 = byi * 32;
    int tx = threadIdx.x & 31, ty = threadIdx.x >> 5;
    #pragma unroll
    for (int i = 0; i < 32; i += 8)
      t[ty + i][tx] = W[(size_t)(by0 + ty + i) * E_ + bx0 + tx];
    __syncthreads();
    #pragma unroll
    for (int i = 0; i < 32; i += 8)
      Wt[(size_t)(bx0 + ty + i) * E_ + by0 + tx] = f2bf(t[tx][ty + i]);
  }
}

// ---------------- fused QKV GEMM: C = Xb(8192x768) @ W(768x768) + bias ----------------
// ASYNC global_load_lds + LDS double-buffer, ONE barrier/iter. No staged VGPRs
// -> spill-proof (R3/R8/R9 all died on register-staged prefetch spills).
// The implicit s_waitcnt vmcnt(0) before s_barrier IS the synchronization: the
// DMA issued at iter it (into buf[1-cur]) has the whole compute phase to land
// and is drained by the barrier at iter it+1. Lane map is identity (DMA deposits
// slot = lane): LDS slot L holds fragment (row=L&15, oct=L>>4) -> conflict-free
// contiguous ds_read_b128 (m97-verified pattern).
__global__ __launch_bounds__(256) void qkv_gemm_kernel(
    const u16* __restrict__ Xb, const u16* __restrict__ WtBase,
    const float* __restrict__ bq, const float* __restrict__ bk, const float* __restrict__ bv,
    u16* __restrict__ Qb, u16* __restrict__ Kb, u16* __restrict__ VtB)
{
  __shared__ u16 lA[2][8 * 512];   // 8 chunks x 1KB per buffer (chunk = 16 rows x 32 k)
  __shared__ u16 lB[2][8 * 512];
  const int z = blockIdx.z;
  const u16* Wt = WtBase + (size_t)z * E_ * E_;
  const float* bias = (z == 0) ? bq : ((z == 1) ? bk : bv);
  const int m0 = blockIdx.x * 128;
  const int n0 = blockIdx.y * 128;
  const int tid = threadIdx.x;
  const int lane = tid & 63;
  const int wave = tid >> 6;
  const int wm = wave & 1, wn = wave >> 1;       // 2x2 waves of 64x64
  const int col0 = lane & 15, quad = lane >> 4;
  const int ls = lane & 15;                      // identity map: row within chunk
  const int lk = lane >> 4;                      // k-octet

  f32x4 acc[4][4];
  #pragma unroll
  for (int i = 0; i < 4; ++i)
    #pragma unroll
    for (int j = 0; j < 4; ++j)
      acc[i][j] = (f32x4){0.f, 0.f, 0.f, 0.f};

  // each wave owns chunks wave*2, wave*2+1 of both matrices
  auto issue = [&](int buf, int k0){
    #pragma unroll
    for (int cc = 0; cc < 2; ++cc){
      int c = wave * 2 + cc;
      gload_lds16(Xb + (size_t)(m0 + c*16 + ls) * E_ + k0 + lk*8, &lA[buf][c*512]);
      gload_lds16(Wt + (size_t)(n0 + c*16 + ls) * E_ + k0 + lk*8, &lB[buf][c*512]);
    }
  };
  issue(0, 0);

  #pragma unroll 1
  for (int it = 0; it < 24; ++it){
    const int cur = it & 1;
    __syncthreads();   // implicit vmcnt(0): buf[cur]'s DMA complete; buf[1-cur]'s readers done
    if (it + 1 < 24) issue(1 - cur, (it + 1) * 32);   // async fill of other buffer
    bf16x8 af[4], bfr[4];
    #pragma unroll
    for (int mi = 0; mi < 4; ++mi)
      af[mi] = *reinterpret_cast<const bf16x8*>(&lA[cur][(wm*4 + mi)*512 + lane*8]);
    #pragma unroll
    for (int ni = 0; ni < 4; ++ni)
      bfr[ni] = *reinterpret_cast<const bf16x8*>(&lB[cur][(wn*4 + ni)*512 + lane*8]);
    #pragma unroll
    for (int mi = 0; mi < 4; ++mi)
      #pragma unroll
      for (int ni = 0; ni < 4; ++ni)
        acc[mi][ni] = __builtin_amdgcn_mfma_f32_16x16x32_bf16(af[mi], bfr[ni], acc[mi][ni], 0, 0, 0);
  }

  // epilogue: C col = n = lane&15, row = m = quad*4+r
  #pragma unroll
  for (int mi = 0; mi < 4; ++mi){
    #pragma unroll
    for (int ni = 0; ni < 4; ++ni){
      int n = n0 + wn*64 + ni*16 + col0;
      float bval = bias[n];
      int h = n >> 6, d = n & 63;
      #pragma unroll
      for (int r = 0; r < 4; ++r){
        int m = m0 + wm*64 + mi*16 + quad*4 + r;
        int b = m >> 9, s = m & 511;
        u16 obf = f2bf(acc[mi][ni][r] + bval);
        size_t bh = (size_t)b * NH_ + h;
        if (z == 0)      Qb[(bh * S_ + s) * D_ + d] = obf;
        else if (z == 1) Kb[(bh * S_ + s) * D_ + d] = obf;
        else             VtB[(bh * D_ + d) * S_ + s] = obf;  // transposed for attention
      }
    }
  }
}

// ---------------- flash attention (unchanged from R9) ----------------
__global__ __launch_bounds__(256) void attn_kernel(
    const u16* __restrict__ Qb, const u16* __restrict__ Kb, const u16* __restrict__ VtB,
    const float* __restrict__ mask, float* __restrict__ out)
{
  __shared__ u16 lK[2][8 * 512];   // 16 KB
  __shared__ u16 lV[2][8 * 512];   // 16 KB
  __shared__ u16 lP[8 * 1024];     // 16 KB: (wave*2+g)*1024, per-wave (no barrier)
  __shared__ float biasS[S_];
  const int bh = blockIdx.x;
  const int qt = blockIdx.y;
  const int b = bh / NH_, h = bh % NH_;
  const int tid = threadIdx.x, lane = tid & 63, wave = tid >> 6;
  const int col0 = lane & 15, quad = lane >> 4;
  const int srow = lane >> 2, soct = lane & 3;   // coalesced staging
  const int sslot = soct*16 + (srow ^ (soct << 1));
  const int rslot = quad*16 + (col0 ^ (quad << 1));
  const float C1 = 0.125f * LOG2E;               // score scale folded with log2e

  for (int i = tid; i < S_; i += 256)
    biasS[i] = mask[b * S_ + i] * (-1.0e9f * LOG2E);   // exp2 domain; visible after iter-0 barrier

  const u16* Kbh = Kb  + (size_t)bh * S_ * D_;
  const u16* Vbh = VtB + (size_t)bh * D_ * S_;

  // Q fragments: 2 groups x 16 rows (B-operand; same layout as A)
  bf16x8 qf[2][2];
  #pragma unroll
  for (int g = 0; g < 2; ++g){
    int qrow = qt*128 + wave*32 + g*16 + col0;
    #pragma unroll
    for (int ks = 0; ks < 2; ++ks)
      qf[g][ks] = *reinterpret_cast<const bf16x8*>(
          Qb + ((size_t)bh * S_ + qrow) * D_ + ks*32 + quad*8);
  }

  // staging: waves 0-1 -> 8 K chunks, waves 2-3 -> 8 Vt chunks
  uint4 rg[4];
  auto issue = [&](int st){
    if (wave < 2){
      #pragma unroll
      for (int gg = 0; gg < 4; ++gg){
        int c = wave*4 + gg, ks = c >> 2, nt = c & 3;
        rg[gg] = *reinterpret_cast<const uint4*>(
            Kbh + (size_t)(st*64 + nt*16 + srow) * D_ + ks*32 + soct*8);
      }
    } else {
      #pragma unroll
      for (int gg = 0; gg < 4; ++gg){
        int c = (wave - 2)*4 + gg, ks2 = c >> 2, nd = c & 3;
        rg[gg] = *reinterpret_cast<const uint4*>(
            Vbh + (size_t)(nd*16 + srow) * S_ + st*64 + ks2*32 + soct*8);
      }
    }
  };
  issue(0);

  f32x4 o[2][4];
  #pragma unroll
  for (int g = 0; g < 2; ++g)
    #pragma unroll
    for (int i = 0; i < 4; ++i) o[g][i] = (f32x4){0.f, 0.f, 0.f, 0.f};
  float psum[2] = {0.f, 0.f};   // per-lane partial row-sums

  #pragma unroll 1
  for (int st = 0; st < 8; ++st){
    const int cur = st & 1;
    if (wave < 2){
      #pragma unroll
      for (int gg = 0; gg < 4; ++gg)
        *reinterpret_cast<uint4*>(&lK[cur][(wave*4 + gg)*512 + sslot*8]) = rg[gg];
    } else {
      #pragma unroll
      for (int gg = 0; gg < 4; ++gg)
        *reinterpret_cast<uint4*>(&lV[cur][((wave - 2)*4 + gg)*512 + sslot*8]) = rg[gg];
    }
    __syncthreads();            // single barrier/iter
    if (st < 7) issue(st + 1);  // prefetch during compute

    // scores transposed, both groups: 64 keys (rows) x 16 q (cols)
    f32x4 sc[2][4];
    #pragma unroll
    for (int g = 0; g < 2; ++g)
      #pragma unroll
      for (int nt = 0; nt < 4; ++nt) sc[g][nt] = (f32x4){0.f, 0.f, 0.f, 0.f};
    #pragma unroll
    for (int ks = 0; ks < 2; ++ks){
      bf16x8 kf[4];
      #pragma unroll
      for (int nt = 0; nt < 4; ++nt)
        kf[nt] = *reinterpret_cast<const bf16x8*>(&lK[cur][(ks*4 + nt)*512 + rslot*8]);
      #pragma unroll
      for (int g = 0; g < 2; ++g)
        #pragma unroll
        for (int nt = 0; nt < 4; ++nt)
          sc[g][nt] = __builtin_amdgcn_mfma_f32_16x16x32_bf16(kf[nt], qf[g][ks], sc[g][nt], 0, 0, 0);
    }

    float4 bb[4];
    #pragma unroll
    for (int nt = 0; nt < 4; ++nt)
      bb[nt] = *reinterpret_cast<const float4*>(&biasS[st*64 + nt*16 + quad*4]);

    #pragma unroll
    for (int g = 0; g < 2; ++g){
      #pragma unroll
      for (int nt = 0; nt < 4; ++nt){
        float p0 = exp2f(sc[g][nt][0] * C1 + bb[nt].x);
        float p1 = exp2f(sc[g][nt][1] * C1 + bb[nt].y);
        float p2 = exp2f(sc[g][nt][2] * C1 + bb[nt].z);
        float p3 = exp2f(sc[g][nt][3] * C1 + bb[nt].w);
        psum[g] += (p0 + p1) + (p2 + p3);
        float2 ab; ab.x = p0; ab.y = p1;
        float2 cd; cd.x = p2; cd.y = p3;
        __hip_bfloat162 h01 = __float22bfloat162_rn(ab);
        __hip_bfloat162 h23 = __float22bfloat162_rn(cd);
        uint2 pw;
        pw.x = *reinterpret_cast<unsigned int*>(&h01);
        pw.y = *reinterpret_cast<unsigned int*>(&h23);
        // A-layout addr: chunk=nt>>1, slot=((nt&1)*2+(quad>>1))*16+q, u16 pos=(quad&1)*4+r
        int addr = (wave*2 + g)*1024 + (nt >> 1)*512
                 + (((nt & 1)*2 + (quad >> 1))*16 + col0)*8 + (quad & 1)*4;
        *reinterpret_cast<uint2*>(&lP[addr]) = pw;
      }
    }

    // PV: shared V fragments serve both groups
    #pragma unroll
    for (int ks2 = 0; ks2 < 2; ++ks2){
      bf16x8 pf0 = *reinterpret_cast<const bf16x8*>(&lP[(wave*2 + 0)*1024 + ks2*512 + lane*8]);
      bf16x8 pf1 = *reinterpret_cast<const bf16x8*>(&lP[(wave*2 + 1)*1024 + ks2*512 + lane*8]);
      #pragma unroll
      for (int nd = 0; nd < 4; ++nd){
        bf16x8 vf = *reinterpret_cast<const bf16x8*>(&lV[cur][(ks2*4 + nd)*512 + rslot*8]);
        o[0][nd] = __builtin_amdgcn_mfma_f32_16x16x32_bf16(pf0, vf, o[0][nd], 0, 0, 0);
        o[1][nd] = __builtin_amdgcn_mfma_f32_16x16x32_bf16(pf1, vf, o[1][nd], 0, 0, 0);
      }
    }
  }

  // epilogue: finish row-sums (once), normalize, store fp32
  #pragma unroll
  for (int g = 0; g < 2; ++g){
    float tot = psum[g];
    tot += __shfl_xor(tot, 16, 64);
    tot += __shfl_xor(tot, 32, 64);
    #pragma unroll
    for (int r = 0; r < 4; ++r){
      int s = qt*128 + wave*32 + g*16 + quad*4 + r;
      float lr = __shfl(tot, (lane & 48) | (quad*4 + r), 64);
      float inv = 1.0f / lr;
      #pragma unroll
      for (int nd = 0; nd < 4; ++nd){
        int d = nd*16 + col0;
        out[((size_t)b * S_ + s) * E_ + h*D_ + d] = o[g][nd][r] * inv;
      }
    }
  }
}

extern "C" void kernel_launch(void* const* d_in, const int* in_sizes, int n_in,
                              void* d_out, int out_size, void* d_ws, size_t ws_size,
                              hipStream_t stream){
  const float* X    = (const float*)d_in[0];
  const float* mask = (const float*)d_in[1];
  const float* Wq   = (const float*)d_in[2];
  const float* bq   = (const float*)d_in[3];
  const float* Wk   = (const float*)d_in[4];
  const float* bk   = (const float*)d_in[5];
  const float* Wv   = (const float*)d_in[6];
  const float* bv   = (const float*)d_in[7];
  float* out = (float*)d_out;

  // workspace layout (bf16): Xb | Wt x3 | Qb | Kb | Vt  (~51.4 MB total)
  u16* Xb = (u16*)d_ws;
  u16* Wt = Xb + (size_t)M_ * E_;
  u16* Qb = Wt + (size_t)3 * E_ * E_;
  u16* Kb = Qb + (size_t)M_ * E_;
  u16* Vt = Kb + (size_t)M_ * E_;

  prep_kernel<<<6144 + 1728, 256, 0, stream>>>(X, Xb, Wq, Wk, Wv, Wt);
  qkv_gemm_kernel<<<dim3(64, 6, 3), 256, 0, stream>>>(Xb, Wt, bq, bk, bv, Qb, Kb, Vt);
  attn_kernel<<<dim3(192, 4), 256, 0, stream>>>(Qb, Kb, Vt, mask, out);
}